// Round 16
// baseline (165.647 us; speedup 1.0000x reference)
//
#include <hip/hip_runtime.h>
#include <math.h>

#define NN 16384
#define NP 8192
#define NL 8192
#define KW 32
#define VC 100000
#define SENT  0xFFFFFFFFu
#define NEVER 0xFFFFFFFEu     // CAS compare that never matches real data -> pure coherent read
#define UMAP_NEGINF 0x007FFFFFu

__device__ __forceinline__ float sigmoidf_(float x){ return 1.0f/(1.0f+expf(-x)); }
__device__ __forceinline__ unsigned int umap(float f){
  unsigned int b = __float_as_uint(f);
  return (b & 0x80000000u) ? ~b : (b | 0x80000000u);
}
__device__ __forceinline__ float uunmap(unsigned int u){
  unsigned int b = (u & 0x80000000u) ? (u & 0x7FFFFFFFu) : ~u;
  return __uint_as_float(b);
}

// ---- K1: setup: ET transpose | WT transposes | node_h->SENT | g_rem/gmax init ----
__global__ void __launch_bounds__(256) k_setup(const float* __restrict__ E, float* __restrict__ ET,
    const float* __restrict__ Wz, const float* __restrict__ Wr, const float* __restrict__ Wh,
    const float* __restrict__ Uz, const float* __restrict__ Ur, const float* __restrict__ Uh,
    float* __restrict__ WT, unsigned int* node_h, int* g_rem, unsigned int* gmax,
    int et_blocks){
  __shared__ float tile[64][65];
  int b = blockIdx.x;
  int lane = threadIdx.x & 63, ty = threadIdx.x >> 6;
  if (b < et_blocks){
    int v0 = b*64;
    for (int h = ty; h < 64; h += 4){
      int v = v0 + lane;
      tile[h][lane] = (v < VC) ? E[(size_t)h*VC + v] : 0.f;
    }
    __syncthreads();
    for (int vv = ty; vv < 64; vv += 4){
      int v = v0 + vv;
      if (v < VC) ET[v*64 + lane] = tile[lane][vv];
    }
  } else if (b < et_blocks + 6){
    int m = b - et_blocks;
    const float* src = (m==0)?Wz:(m==1)?Wr:(m==2)?Wh:(m==3)?Uz:(m==4)?Ur:Uh;
    float* dst = WT + m*4096;
    for (int h = ty; h < 64; h += 4) tile[h][lane] = src[h*64 + lane];
    __syncthreads();
    for (int k = ty; k < 64; k += 4) dst[k*64 + lane] = tile[lane][k];
  } else if (b < et_blocks + 6 + 1024){
    // ALL node rows -> SENT, vectorized: NN*64 dwords = 262,144 uint4
    size_t idx = (size_t)(b - et_blocks - 6)*256 + threadIdx.x;
    uint4 s = make_uint4(SENT, SENT, SENT, SENT);
    ((uint4*)node_h)[idx] = s;
  } else {
    int idx = (b - et_blocks - 6 - 1024)*256 + threadIdx.x;       // 2 blocks
    if (idx < 512) gmax[idx] = UMAP_NEGINF;
    if (idx == 0) *g_rem = NP;
  }
}

// ---- publish: per-lane atomicExch -> value lands at the L3 coherence point ----
__device__ __forceinline__ void publish_row(unsigned int* row, int lane, float h){
  atomicExch(&row[lane], __float_as_uint(h));
}

// ---- shared GRU math ----
__device__ __forceinline__ float gru_compute(int lane,
    int c0,int c1,int c2,int c3,
    float chv0,float chv1,float chv2,float chv3,
    float q, float pzv, float prv, float pcv,
    const float* __restrict__ UzT, const float* __restrict__ UrT,
    const float* __restrict__ UhT)
{
  float d0=q*chv0, d1=q*chv1, d2=q*chv2, d3=q*chv3;
  #pragma unroll
  for (int off=32; off; off>>=1){
    d0 += __shfl_xor(d0, off); d1 += __shfl_xor(d1, off);
    d2 += __shfl_xor(d2, off); d3 += __shfl_xor(d3, off);
  }
  float l0 = (c0>=0)? sigmoidf_(d0) : -1e30f;
  float l1 = (c1>=0)? sigmoidf_(d1) : -1e30f;
  float l2 = (c2>=0)? sigmoidf_(d2) : -1e30f;
  float l3 = (c3>=0)? sigmoidf_(d3) : -1e30f;
  float mx = fmaxf(fmaxf(l0,l1), fmaxf(l2,l3));
  float e0=expf(l0-mx), e1=expf(l1-mx), e2=expf(l2-mx), e3=expf(l3-mx);
  float inv = 1.f/(e0+e1+e2+e3);
  float ht = (e0*chv0 + e1*chv1 + e2*chv2 + e3*chv3)*inv;
  float az0=0.f, az1=0.f, ar0=0.f, ar1=0.f;
  #pragma unroll 8
  for (int k=0;k<64;k+=2){
    float h0 = __shfl(ht, k), h1 = __shfl(ht, k+1);
    az0 += h0 * UzT[k*64+lane];     az1 += h1 * UzT[(k+1)*64+lane];
    ar0 += h0 * UrT[k*64+lane];     ar1 += h1 * UrT[(k+1)*64+lane];
  }
  float z = sigmoidf_(pzv + az0+az1);
  float r = sigmoidf_(prv + ar0+ar1);
  float rh = r*ht;
  float ac0=0.f, ac1=0.f, ac2=0.f, ac3=0.f;
  #pragma unroll 8
  for (int k=0;k<64;k+=4){
    float r0 = __shfl(rh, k),   r1 = __shfl(rh, k+1);
    float r2 = __shfl(rh, k+2), r3 = __shfl(rh, k+3);
    ac0 += r0 * UhT[k*64+lane];     ac1 += r1 * UhT[(k+1)*64+lane];
    ac2 += r2 * UhT[(k+2)*64+lane]; ac3 += r3 * UhT[(k+3)*64+lane];
  }
  float cc = tanhf(pcv + (ac0+ac1)+(ac2+ac3));
  return z*ht + (1.f-z)*cc;
}

// ---- K2: FUSED gather + node transform + single-dispatch dataflow scan ----
// Minimal-RTT sync protocol (r12/r15 evidence: poll traffic & contention are NOT the
// limiter; per-hop RTTs are):
//  publish : per-lane atomicExch (1 RTT; no ordering protocol needed — each dword
//            independently valid when != SENT, rows monotone SENT->final)
//  detect+read: each still-SENT lane CAS-reads ITS OWN word; the detecting CAS IS
//            the data read (no separate repair pass). All 4 children concurrent.
//  cadence : 16 fast rounds (s_sleep(1) ~64cyc) then park at s_sleep(8) ~512cyc.
// Failsafe: bounded rounds; on timeout leave row SENT -> k_finish backstop.
__device__ __forceinline__ void fused_body(int wid, int lane, float xev,
    const float* __restrict__ WzT, const float* __restrict__ WrT,
    const float* __restrict__ WhT, const float* __restrict__ Wa,
    const float* __restrict__ bz, const float* __restrict__ br,
    const float* __restrict__ bh,
    const float* __restrict__ UzT, const float* __restrict__ UrT,
    const float* __restrict__ UhT, const int* __restrict__ tree,
    unsigned int* nhu, float* pz, float* pr, float* pc, float* qa,
    int* g_rem, unsigned int* gmax)
{
  if (wid < NL){
    float az0=0.f, az1=0.f, ah0=0.f, ah1=0.f;
    #pragma unroll 8
    for (int k=0;k<64;k+=2){
      float x0 = __shfl(xev, k), x1 = __shfl(xev, k+1);
      az0 += x0 * WzT[k*64+lane];     az1 += x1 * WzT[(k+1)*64+lane];
      ah0 += x0 * WhT[k*64+lane];     ah1 += x1 * WhT[(k+1)*64+lane];
    }
    float z = sigmoidf_(az0+az1 + bz[lane]);
    float c = tanhf(ah0+ah1 + bh[lane]);
    publish_row(&nhu[(size_t)wid*64], lane, (1.f-z)*c);
    return;
  }
  int i = wid - NL;
  float az=0.f, ar=0.f, ah=0.f, aq=0.f;
  #pragma unroll 4
  for (int k=0;k<64;++k){
    float xk = __shfl(xev, k);
    az += xk * WzT[k*64+lane];
    ar += xk * WrT[k*64+lane];
    ah += xk * WhT[k*64+lane];
    aq += xk * Wa [k*64+lane];
  }
  float q = aq, pzv = az + bz[lane], prv = ar + br[lane], pcv = ah + bh[lane];
  // store for the finish backstop (fast path consumes the registers)
  pz[i*64+lane] = pzv; pr[i*64+lane] = prv; pc[i*64+lane] = pcv; qa[i*64+lane] = q;
  const int* tr = tree + i*5;
  int c0=tr[0], c1=tr[1], c2=tr[2], c3=tr[3];
  // fast path: plain wave-loads (stale can only read SENT -> routed to poll)
  unsigned int u0 = (c0>=0)? nhu[(size_t)c0*64+lane] : 0u;
  unsigned int u1 = (c1>=0)? nhu[(size_t)c1*64+lane] : 0u;
  unsigned int u2 = (c2>=0)? nhu[(size_t)c2*64+lane] : 0u;
  unsigned int u3 = (c3>=0)? nhu[(size_t)c3*64+lane] : 0u;
  bool anyS = __any((int)(u0==SENT)) || __any((int)(u1==SENT)) ||
              __any((int)(u2==SENT)) || __any((int)(u3==SENT));
  if (anyS){
    int rounds = 0;
    for(;;){
      // detect+read combined: only still-SENT lanes issue a coherent CAS-read
      if (c0>=0 && u0==SENT) u0 = atomicCAS(&nhu[(size_t)c0*64+lane], NEVER, NEVER);
      if (c1>=0 && u1==SENT) u1 = atomicCAS(&nhu[(size_t)c1*64+lane], NEVER, NEVER);
      if (c2>=0 && u2==SENT) u2 = atomicCAS(&nhu[(size_t)c2*64+lane], NEVER, NEVER);
      if (c3>=0 && u3==SENT) u3 = atomicCAS(&nhu[(size_t)c3*64+lane], NEVER, NEVER);
      bool pend = __any((int)(u0==SENT)) || __any((int)(u1==SENT)) ||
                  __any((int)(u2==SENT)) || __any((int)(u3==SENT));
      if (!pend) break;
      if (++rounds > (1<<14)) return;                // failsafe -> finish backstop
      if (rounds < 16) __builtin_amdgcn_s_sleep(1);  // ~64 cyc: fast detect
      else             __builtin_amdgcn_s_sleep(8);  // ~512 cyc: parked
    }
  }
  float h = gru_compute(lane, c0,c1,c2,c3,
                        __uint_as_float(u0), __uint_as_float(u1),
                        __uint_as_float(u2), __uint_as_float(u3),
                        q, pzv, prv, pcv, UzT, UrT, UhT);
  publish_row(&nhu[(size_t)(NL+i)*64], lane, h);
  atomicMax(&gmax[(i&7)*64 + lane], umap(h));        // fused max-pool
  if (lane==0) atomicAdd(g_rem, -1);
}

__global__ void __launch_bounds__(256) k_fused(const float* __restrict__ xw,
    const int* __restrict__ xi, const float* __restrict__ ET,
    const float* __restrict__ WzT, const float* __restrict__ WrT,
    const float* __restrict__ WhT, const float* __restrict__ Wa,
    const float* __restrict__ bz, const float* __restrict__ br,
    const float* __restrict__ bh,
    const float* __restrict__ UzT, const float* __restrict__ UrT,
    const float* __restrict__ UhT, const int* __restrict__ tree,
    unsigned int* nhu, float* pz, float* pr, float* pc, float* qa,
    int* g_rem, unsigned int* gmax)
{
  int wid = blockIdx.x*4 + (threadIdx.x>>6);
  int lane = threadIdx.x & 63;
  if (wid >= NN) return;
  int   idxl = (lane < KW) ? xi[wid*KW + lane] : 0;
  float wl   = (lane < KW) ? xw[wid*KW + lane] : 0.f;
  float xev = 0.f;
  #pragma unroll 8
  for (int k = 0; k < KW; ++k){
    int   vk = __shfl(idxl, k);
    float wk = __shfl(wl,   k);
    xev += wk * ET[vk*64 + lane];
  }
  fused_body(wid, lane, xev, WzT,WrT,WhT,Wa, bz,br,bh, UzT,UrT,UhT, tree,
             nhu, pz,pr,pc,qa, g_rem, gmax);
}

__global__ void __launch_bounds__(256) k_fused_direct(const float* __restrict__ xw,
    const int* __restrict__ xi, const float* __restrict__ E,
    const float* __restrict__ WzT, const float* __restrict__ WrT,
    const float* __restrict__ WhT, const float* __restrict__ Wa,
    const float* __restrict__ bz, const float* __restrict__ br,
    const float* __restrict__ bh,
    const float* __restrict__ UzT, const float* __restrict__ UrT,
    const float* __restrict__ UhT, const int* __restrict__ tree,
    unsigned int* nhu, float* pz, float* pr, float* pc, float* qa,
    int* g_rem, unsigned int* gmax)
{
  int wid = blockIdx.x*4 + (threadIdx.x>>6);
  int lane = threadIdx.x & 63;
  if (wid >= NN) return;
  const float* wv = xw + wid*KW;
  const int*   v  = xi + wid*KW;
  const float* Erow = E + (size_t)lane*VC;
  float xev = 0.f;
  for (int k = 0; k < KW; ++k) xev += wv[k] * Erow[v[k]];
  fused_body(wid, lane, xev, WzT,WrT,WhT,Wa, bz,br,bh, UzT,UrT,UhT, tree,
             nhu, pz,pr,pc,qa, g_rem, gmax);
}

// ---- K3: finish = single-block cleanup backstop + final max reduce + head ----
// Runs after a dispatch boundary (start-of-dispatch invalidate => plain loads see L3).
__global__ void __launch_bounds__(256) k_finish(const int* __restrict__ tree,
    const float* __restrict__ qa, const float* __restrict__ pz,
    const float* __restrict__ pr, const float* __restrict__ pc,
    const float* __restrict__ UzT, const float* __restrict__ UrT,
    const float* __restrict__ UhT,
    unsigned int* nhu, int* g_rem, unsigned int* gmax,
    const float* __restrict__ Wout, const float* __restrict__ bout,
    float* __restrict__ out)
{
  __shared__ int cnt_s;
  int w = threadIdx.x >> 6, lane = threadIdx.x & 63;
  int rem = *g_rem;
  while (rem > 0){
    if (threadIdx.x == 0) cnt_s = 0;
    __syncthreads();
    int my = 0;
    for (int i = w; i < NP; i += 4){
      if (nhu[(size_t)(NL+i)*64] != SENT) continue;     // already done
      const int* tr = tree + i*5;
      int c0=tr[0], c1=tr[1], c2=tr[2], c3=tr[3];
      bool ready = (c0<0 || nhu[(size_t)c0*64] != SENT) &&
                   (c1<0 || nhu[(size_t)c1*64] != SENT) &&
                   (c2<0 || nhu[(size_t)c2*64] != SENT) &&
                   (c3<0 || nhu[(size_t)c3*64] != SENT);
      if (!ready) continue;
      float chv0 = (c0>=0)? __uint_as_float(nhu[(size_t)c0*64+lane]) : 0.f;
      float chv1 = (c1>=0)? __uint_as_float(nhu[(size_t)c1*64+lane]) : 0.f;
      float chv2 = (c2>=0)? __uint_as_float(nhu[(size_t)c2*64+lane]) : 0.f;
      float chv3 = (c3>=0)? __uint_as_float(nhu[(size_t)c3*64+lane]) : 0.f;
      float h = gru_compute(lane, c0,c1,c2,c3, chv0,chv1,chv2,chv3,
                            qa[i*64+lane], pz[i*64+lane], pr[i*64+lane], pc[i*64+lane],
                            UzT, UrT, UhT);
      nhu[(size_t)(NL+i)*64+lane] = __float_as_uint(h); // same-block readers
      atomicMax(&gmax[(i&7)*64+lane], umap(h));
      ++my;
    }
    if (lane==0 && my) atomicAdd(&cnt_s, my);
    __syncthreads();
    rem -= cnt_s;
    if (cnt_s == 0) break;            // guarantees termination
    __syncthreads();
  }
  __syncthreads();
  if (w == 0){
    float m = -1e30f;
    #pragma unroll
    for (int c = 0; c < 8; ++c){
      unsigned int g = atomicCAS(&gmax[c*64+lane], NEVER, NEVER);  // coherent read
      m = fmaxf(m, uunmap(g));
    }
    float s0 = Wout[0*64+lane]*m, s1 = Wout[1*64+lane]*m;
    float s2 = Wout[2*64+lane]*m, s3 = Wout[3*64+lane]*m;
    #pragma unroll
    for (int off=32; off; off>>=1){
      s0 += __shfl_xor(s0, off); s1 += __shfl_xor(s1, off);
      s2 += __shfl_xor(s2, off); s3 += __shfl_xor(s3, off);
    }
    s0 += bout[0]; s1 += bout[1]; s2 += bout[2]; s3 += bout[3];
    float mx = fmaxf(fmaxf(s0,s1), fmaxf(s2,s3));
    float e0=expf(s0-mx), e1=expf(s1-mx), e2=expf(s2-mx), e3=expf(s3-mx);
    float inv = 1.f/(e0+e1+e2+e3);
    if (lane==0){
      out[0]=e0*inv; out[1]=e1*inv; out[2]=e2*inv; out[3]=e3*inv;
    }
  }
}

__global__ void k_ws_sentinel(float* out, float wsmb){
  if (threadIdx.x < 4) out[threadIdx.x] = wsmb;
}

extern "C" void kernel_launch(void* const* d_in, const int* in_sizes, int n_in,
                              void* d_out, int out_size, void* d_ws, size_t ws_size,
                              hipStream_t stream){
  const float* x_word = (const float*)d_in[0];
  const int*   x_index= (const int*)d_in[1];
  const int*   tree   = (const int*)d_in[2];
  const float* E      = (const float*)d_in[3];
  const float* Wz     = (const float*)d_in[4];
  const float* Uz     = (const float*)d_in[5];
  const float* bz     = (const float*)d_in[6];
  const float* Wr     = (const float*)d_in[7];
  const float* Ur     = (const float*)d_in[8];
  const float* br     = (const float*)d_in[9];
  const float* Wh     = (const float*)d_in[10];
  const float* Uh     = (const float*)d_in[11];
  const float* bh     = (const float*)d_in[12];
  const float* Wa     = (const float*)d_in[13];
  const float* Wout   = (const float*)d_in[14];
  const float* bout   = (const float*)d_in[15];
  float* out = (float*)d_out;

  float* ws = (float*)d_ws;

  // Layout: ET (6,400,000 f, full path only; read by k_fused) | qa/pz/pr/pc (2,097,152)
  //       | nodeh (1,048,576) | WT (24,576) | g_rem (1) | gmax (512).
  const size_t R0_FULL = 6400000;
  const size_t TAIL = (size_t)2097152 + 1048576 + 24576 + 1 + 512;
  const size_t FULL_NEED = (R0_FULL + TAIL) * 4;   // ~38.3 MB (r12-r15 proved available)
  const size_t FB_NEED   = TAIL * 4;               // ~12.7 MB

  bool full = (ws_size >= FULL_NEED);
  bool fb   = (!full && ws_size >= FB_NEED);
  if (!full && !fb){
    k_ws_sentinel<<<1, 64, 0, stream>>>(out, (float)(ws_size >> 20));
    return;
  }

  float* ET = ws;                                  // full path only
  size_t r0 = full ? R0_FULL : 0;
  float* qa    = ws + r0;                          // 4 x 524,288
  float* pz    = qa + 524288;
  float* pr    = pz + 524288;
  float* pc    = pr + 524288;
  unsigned int* nhu = (unsigned int*)(pc + 524288);  // NN*64
  float* WT    = (float*)(nhu + (size_t)NN*64);    // 24,576
  int*   g_rem = (int*)(WT + 24576);               // 1
  unsigned int* gmax = (unsigned int*)(g_rem + 1); // 512
  float* WzT = WT,       *WrT = WT+4096,  *WhT = WT+8192;
  float* UzT = WT+12288, *UrT = WT+16384, *UhT = WT+20480;

  int et_blocks = full ? (VC+63)/64 : 0;           // 1563 or 0
  k_setup<<<et_blocks + 6 + 1024 + 2, 256, 0, stream>>>(
      E, ET, Wz, Wr, Wh, Uz, Ur, Uh, WT, nhu, g_rem, gmax, et_blocks);
  if (full)
    k_fused<<<NN/4, 256, 0, stream>>>(x_word, x_index, ET, WzT, WrT, WhT, Wa,
                                      bz, br, bh, UzT, UrT, UhT, tree,
                                      nhu, pz, pr, pc, qa, g_rem, gmax);
  else
    k_fused_direct<<<NN/4, 256, 0, stream>>>(x_word, x_index, E, WzT, WrT, WhT, Wa,
                                             bz, br, bh, UzT, UrT, UhT, tree,
                                             nhu, pz, pr, pc, qa, g_rem, gmax);
  k_finish<<<1, 256, 0, stream>>>(tree, qa, pz, pr, pc, UzT, UrT, UhT,
                                  nhu, g_rem, gmax, Wout, bout, out);
}